// Round 11
// baseline (474.890 us; speedup 1.0000x reference)
//
#include <hip/hip_runtime.h>
#include <stdint.h>

#define E_ 8
#define DIN 256
#define DOUT 256
#define HID 512
#define GHID 128
#define NTOK 32768
#define NROW (NTOK * 2)
#define TABCAP 520
#define TAB256 264
#define CNT_STRIDE 32

typedef float f32x4 __attribute__((ext_vector_type(4)));
typedef short bf16x8 __attribute__((ext_vector_type(8)));

// fp32 -> bf16 round-to-nearest-even
__device__ __forceinline__ unsigned short f2bf(float f) {
    unsigned int u = __float_as_uint(f);
    u += 0x7FFFu + ((u >> 16) & 1u);
    return (unsigned short)(u >> 16);
}

// async global->LDS, 16B per lane; LDS base must be wave-uniform (HW adds lane*16)
__device__ __forceinline__ void gload_lds16(const void* g, void* l) {
    __builtin_amdgcn_global_load_lds(
        (const __attribute__((address_space(1))) unsigned int*)g,
        (__attribute__((address_space(3))) unsigned int*)l, 16, 0, 0);
}

// ---------- weight transpose + bf16 convert: W[e][K][N] -> WT[e][N][K] ----------
__global__ __launch_bounds__(256) void k_transpose_bf16(
    const float* __restrict__ src, unsigned short* __restrict__ dst, int K, int N) {
    __shared__ float tile[64][65];
    int e = blockIdx.z;
    int k0 = blockIdx.x * 64, n0 = blockIdx.y * 64;
    const float* s = src + (size_t)e * K * N;
    unsigned short* d = dst + (size_t)e * N * K;
    int col = threadIdx.x & 63, ri = threadIdx.x >> 6;
#pragma unroll
    for (int it = 0; it < 16; ++it) {
        int row = it * 4 + ri;
        tile[row][col] = s[(size_t)(k0 + row) * N + n0 + col];
    }
    __syncthreads();
#pragma unroll
    for (int it = 0; it < 16; ++it) {
        int nrow = it * 4 + ri;
        d[(size_t)(n0 + nrow) * K + k0 + col] = f2bf(tile[col][nrow]);
    }
}

// ---------- gate layer 1: h = relu(x @ gW1 + gb1), fp32, register-blocked ----------
__global__ __launch_bounds__(256) void k_gate1(
    const float* __restrict__ x, const float* __restrict__ gW1,
    const float* __restrict__ gb1, float* __restrict__ hG) {
    __shared__ float xT[32][132];   // [kk][tok]
    __shared__ float ws[32][132];   // [kk][hid] (128 used)
    int t = threadIdx.x;
    int tokBase = blockIdx.x * 128;
    int tx = t & 15, ty = t >> 4;
    float acc[8][8];
#pragma unroll
    for (int i = 0; i < 8; ++i)
#pragma unroll
        for (int j = 0; j < 8; ++j) acc[i][j] = 0.f;

    int stok = t >> 1;
    int skh = (t & 1) * 16;
    int wkk = t >> 3;
    int wh = (t & 7) * 16;

    for (int k0 = 0; k0 < DIN; k0 += 32) {
        const float* xr = x + (size_t)(tokBase + stok) * DIN + k0 + skh;
        float4 a0 = ((const float4*)xr)[0];
        float4 a1 = ((const float4*)xr)[1];
        float4 a2 = ((const float4*)xr)[2];
        float4 a3 = ((const float4*)xr)[3];
        xT[skh + 0][stok] = a0.x;  xT[skh + 1][stok] = a0.y;
        xT[skh + 2][stok] = a0.z;  xT[skh + 3][stok] = a0.w;
        xT[skh + 4][stok] = a1.x;  xT[skh + 5][stok] = a1.y;
        xT[skh + 6][stok] = a1.z;  xT[skh + 7][stok] = a1.w;
        xT[skh + 8][stok] = a2.x;  xT[skh + 9][stok] = a2.y;
        xT[skh + 10][stok] = a2.z; xT[skh + 11][stok] = a2.w;
        xT[skh + 12][stok] = a3.x; xT[skh + 13][stok] = a3.y;
        xT[skh + 14][stok] = a3.z; xT[skh + 15][stok] = a3.w;
        const float* wr = gW1 + (size_t)(k0 + wkk) * GHID + wh;
        *(float4*)&ws[wkk][wh + 0]  = ((const float4*)wr)[0];
        *(float4*)&ws[wkk][wh + 4]  = ((const float4*)wr)[1];
        *(float4*)&ws[wkk][wh + 8]  = ((const float4*)wr)[2];
        *(float4*)&ws[wkk][wh + 12] = ((const float4*)wr)[3];
        __syncthreads();
#pragma unroll 4
        for (int kk = 0; kk < 32; ++kk) {
            f32x4 wv0 = *(const f32x4*)&ws[kk][tx * 8];
            f32x4 wv1 = *(const f32x4*)&ws[kk][tx * 8 + 4];
            f32x4 xv0 = *(const f32x4*)&xT[kk][ty * 8];
            f32x4 xv1 = *(const f32x4*)&xT[kk][ty * 8 + 4];
            float xs[8] = {xv0.x, xv0.y, xv0.z, xv0.w, xv1.x, xv1.y, xv1.z, xv1.w};
            float wsv[8] = {wv0.x, wv0.y, wv0.z, wv0.w, wv1.x, wv1.y, wv1.z, wv1.w};
#pragma unroll
            for (int i = 0; i < 8; ++i)
#pragma unroll
                for (int j = 0; j < 8; ++j) acc[i][j] += xs[i] * wsv[j];
        }
        __syncthreads();
    }
    float4 b0 = *(const float4*)&gb1[tx * 8];
    float4 b1 = *(const float4*)&gb1[tx * 8 + 4];
#pragma unroll
    for (int i = 0; i < 8; ++i) {
        int tok = tokBase + ty * 8 + i;
        float4 o0, o1;
        o0.x = fmaxf(acc[i][0] + b0.x, 0.f); o0.y = fmaxf(acc[i][1] + b0.y, 0.f);
        o0.z = fmaxf(acc[i][2] + b0.z, 0.f); o0.w = fmaxf(acc[i][3] + b0.w, 0.f);
        o1.x = fmaxf(acc[i][4] + b1.x, 0.f); o1.y = fmaxf(acc[i][5] + b1.y, 0.f);
        o1.z = fmaxf(acc[i][6] + b1.z, 0.f); o1.w = fmaxf(acc[i][7] + b1.w, 0.f);
        float* hr = &hG[(size_t)tok * GHID + tx * 8];
        ((float4*)hr)[0] = o0;
        ((float4*)hr)[1] = o1;
    }
}

// ---------- gate layer 2 + top2 + counts ----------
__global__ __launch_bounds__(256) void k_gate2(
    const float* __restrict__ hG, const float* __restrict__ gW2,
    const float* __restrict__ gb2, int2* __restrict__ tokE,
    float2* __restrict__ tokW, int* __restrict__ cnt) {
    __shared__ float hs[64][132];
    __shared__ float wg[GHID * E_];
    __shared__ int lcnt[E_];
    int t = threadIdx.x;
    int tokBase = blockIdx.x * 64;
#pragma unroll
    for (int i = 0; i < 4; ++i) wg[i * 256 + t] = gW2[i * 256 + t];
    if (t < E_) lcnt[t] = 0;
#pragma unroll
    for (int it = 0; it < 8; ++it) {
        int idx = it * 256 + t;
        int tok = idx >> 5, col = (idx & 31) * 4;
        float4 v = *(const float4*)&hG[(size_t)(tokBase + tok) * GHID + col];
        *(float4*)&hs[tok][col] = v;
    }
    __syncthreads();
    int tok = t >> 2, part = t & 3;
    float s[8];
#pragma unroll
    for (int e = 0; e < E_; ++e) s[e] = 0.f;
    const float* hr = &hs[tok][part * 32];
#pragma unroll 2
    for (int jq = 0; jq < 8; ++jq) {
        f32x4 hv = *(const f32x4*)&hr[jq * 4];
#pragma unroll
        for (int j = 0; j < 4; ++j) {
            float h = hv[j];
            int hidx = part * 32 + jq * 4 + j;
            f32x4 w0 = *(const f32x4*)&wg[hidx * 8];
            f32x4 w1 = *(const f32x4*)&wg[hidx * 8 + 4];
            s[0] += h * w0.x; s[1] += h * w0.y; s[2] += h * w0.z; s[3] += h * w0.w;
            s[4] += h * w1.x; s[5] += h * w1.y; s[6] += h * w1.z; s[7] += h * w1.w;
        }
    }
#pragma unroll
    for (int e = 0; e < E_; ++e) {
        s[e] += __shfl_xor(s[e], 1);
        s[e] += __shfl_xor(s[e], 2);
    }
    if (part == 0) {
        float l[8];
#pragma unroll
        for (int e = 0; e < E_; ++e) l[e] = s[e] + gb2[e];
        int i1 = 0; float b1v = l[0];
#pragma unroll
        for (int e = 1; e < E_; ++e) if (l[e] > b1v) { b1v = l[e]; i1 = e; }
        int i2 = -1; float b2v = -3.4e38f;
#pragma unroll
        for (int e = 0; e < E_; ++e) if (e != i1 && l[e] > b2v) { b2v = l[e]; i2 = e; }
        float mm = fmaxf(b1v, b2v);
        float p1 = expf(b1v - mm), p2 = expf(b2v - mm);
        float inv = 1.f / (p1 + p2);
        int gtok = tokBase + tok;
        tokE[gtok] = make_int2(i1, i2);
        tokW[gtok] = make_float2(p1 * inv, p2 * inv);
        atomicAdd(&lcnt[i1], 1);
        atomicAdd(&lcnt[i2], 1);
    }
    __syncthreads();
    if (t < E_) atomicAdd(&cnt[t * CNT_STRIDE], lcnt[t]);
}

// ---------- prefix offsets, tile work table (256-row tiles), aux outputs ----------
// Tab order: (k,e) lexicographic round-robin -> tab[i].expert == i%8 while all
// experts still have tiles; with the k_gemm remap (xcd = tIdx%8) this pins each
// expert to one XCD L2. NT <= 65536/256 + 7 = 263 <= TAB256.
__global__ void k_route_setup(const int* __restrict__ cnt, int* __restrict__ offs,
                              int* __restrict__ fill, int2* __restrict__ tab,
                              int* __restrict__ NT, float* __restrict__ outTail) {
    int t = threadIdx.x;   // 64 threads
    int c[E_], nt[E_];
#pragma unroll
    for (int e = 0; e < E_; ++e) {
        c[e] = cnt[e * CNT_STRIDE];
        nt[e] = (c[e] + 255) >> 8;
    }
    if (t == 0) {
        int off = 0, ntp = 0;
        float bl = 0.f;
#pragma unroll
        for (int e = 0; e < E_; ++e) {
            offs[e] = off; off += c[e];
            fill[e] = 0;
            ntp += nt[e];
            float u = (float)c[e] / 32768.f;
            outTail[8388609 + e] = u;
            float dd = u - 0.125f;
            bl += dd * dd;
        }
        outTail[8388608] = bl * (0.01f / 8.f);
        *NT = ntp;
    }
    int maxnt = 0;
#pragma unroll
    for (int e = 0; e < E_; ++e) maxnt = max(maxnt, nt[e]);
    for (int k = t; k < maxnt; k += 64) {
        int p = 0;
#pragma unroll
        for (int e = 0; e < E_; ++e) p += min(nt[e], k);
#pragma unroll
        for (int e = 0; e < E_; ++e) {
            if (k < nt[e]) {
                tab[p] = make_int2(e, k);
                ++p;
            }
        }
    }
}

// ---------- gather: assign rows, record token/weight, copy x rows to bf16 ----------
__global__ __launch_bounds__(256) void k_gather(
    const float* __restrict__ x, const int2* __restrict__ tokE,
    const float2* __restrict__ tokW, const int* __restrict__ offs,
    int* __restrict__ fill, int* __restrict__ rowTok, float* __restrict__ rowW,
    unsigned short* __restrict__ xg) {
    __shared__ int lc[E_], lbase[E_], lfill[E_];
    __shared__ int srow[512];
    int t = threadIdx.x;
    int tokBase = blockIdx.x * 256;
    if (t < E_) { lc[t] = 0; lfill[t] = 0; }
    __syncthreads();
    for (int s = t; s < 512; s += 256) {
        int token = tokBase + (s >> 1);
        int2 ee = tokE[token];
        int e = (s & 1) ? ee.y : ee.x;
        atomicAdd(&lc[e], 1);
    }
    __syncthreads();
    if (t < E_) lbase[t] = atomicAdd(&fill[t], lc[t]);
    __syncthreads();
    for (int s = t; s < 512; s += 256) {
        int token = tokBase + (s >> 1);
        int2 ee = tokE[token];
        float2 wv = tokW[token];
        int e; float w;
        if (s & 1) { e = ee.y; w = wv.y; } else { e = ee.x; w = wv.x; }
        int r = atomicAdd(&lfill[e], 1);
        int row = offs[e] + lbase[e] + r;
        srow[s] = row;
        rowTok[row] = token;
        rowW[row] = w;
    }
    __syncthreads();
    int wid = t >> 6, lane = t & 63;
    for (int s = wid; s < 512; s += 4) {
        int row = srow[s];
        int token = tokBase + (s >> 1);
        float4 v = ((const float4*)x)[(size_t)token * 64 + lane];
        ushort4 o;
        o.x = f2bf(v.x); o.y = f2bf(v.y); o.z = f2bf(v.z); o.w = f2bf(v.w);
        ((ushort4*)xg)[(size_t)row * 64 + lane] = o;
    }
}

// ---------- grouped GEMM, 256x256 tile, BK=64, 8 waves, 2-buf LDS (m248 shape) ----------
// Amortization-first: per step each wave does 64 MFMA + 24KB ds_read (~2300 cy of
// real work) against the ~1000cy fixed barrier/drain cost -> the per-step stall
// that pinned the small tiles at ~82us is amortized. m248 measured this shape
// (grouped, 2ph, 256^2, BK=64) at 666 TF refcheck'd. 1 block/CU (128KB LDS),
// acc[8][4] = 128 AGPR + ~80 VGPR <= 256 -> 2 waves/SIMD.
// 8-chunk XOR swizzle (R8-proven): elem-chunk c of row r stored at chunk c^(r&7);
// residual 2-way (rows r, r+8) = free. Staging source is per-lane swizzled, LDS
// linear (G21). XCD remap: xcd = flat%8 = tIdx%8 + expert-interleaved tab.
// mode 0: Hout = relu(acc+bias) bf16; mode 1: atomicAdd(out, (acc+bias)*rowW)
template <int NCT>
__global__ __launch_bounds__(512, 2) void k_gemm(
    const unsigned short* __restrict__ A, const unsigned short* __restrict__ BT,
    const float* __restrict__ bias, const int* __restrict__ offs,
    const int* __restrict__ cnt, const int2* __restrict__ tab,
    const int* __restrict__ NT, int N, int K, int mode,
    unsigned short* __restrict__ Hout, float* __restrict__ outF,
    const int* __restrict__ rowTok, const float* __restrict__ rowW) {
    __shared__ __align__(16) unsigned short As[2][256 * 64];  // 32 KB per buf
    __shared__ __align__(16) unsigned short Bs[2][256 * 64];  // 32 KB per buf

    // flat = xcd + 8*(ct + NCT*qq) -> (ct, tIdx = 8*qq + xcd). Bijection for
    // gridDim.y = TAB256 = 264 = 33*8.
    unsigned flat = blockIdx.x + (unsigned)NCT * blockIdx.y;
    unsigned xcd = flat % 8u;
    unsigned q = flat / 8u;
    unsigned ct = q % (unsigned)NCT;
    unsigned tIdx = (q / (unsigned)NCT) * 8u + xcd;

    if (tIdx >= (unsigned)*NT || tIdx >= (unsigned)TAB256) return;
    int2 ent = tab[tIdx];
    int e = ent.x, rt = ent.y;
    int cntE = cnt[e * CNT_STRIDE];
    int rowStart = offs[e] + rt * 256;
    int valid = cntE - rt * 256;
    if (valid > 256) valid = 256;

    int t = threadIdx.x;
    int lane = t & 63, wid = t >> 6;          // 8 waves
    int quad = lane >> 4, l15 = lane & 15;
    int waveM = wid >> 2, waveN = wid & 3;    // 2M x 4N: wave owns 128 rows x 64 cols

    const unsigned short* Ablk = A + (size_t)rowStart * K;
    const unsigned short* Bblk = BT + ((size_t)e * N + (size_t)ct * 256) * K;

    // staging: tile = 256 rows x 64 elems = 2048 slots of 16B; 512 threads x 4 iters.
    // slot = it*512 + t -> row = slot>>3, LDS position p = slot&7, source chunk
    // c = p ^ (row&7) (involution). LDS addr = slot*16 bytes -> wave-uniform base
    // (it*512 + wid*64)*8 elems + HW lane*16.
    const unsigned short* gaP[4];
    const unsigned short* gbP[4];
    int laP[4];
#pragma unroll
    for (int it = 0; it < 4; ++it) {
        int slot = it * 512 + t;
        int row = slot >> 3;
        int chk = (slot & 7) ^ (row & 7);
        int arow = min(row, valid - 1);
        gaP[it] = Ablk + (size_t)arow * K + chk * 8;
        gbP[it] = Bblk + (size_t)row * K + chk * 8;
        laP[it] = (it * 512 + wid * 64) * 8;
    }

    auto stage = [&](int b, int kt) {
#pragma unroll
        for (int it = 0; it < 4; ++it) {
            gload_lds16(gaP[it] + kt, &As[b][laP[it]]);
            gload_lds16(gbP[it] + kt, &Bs[b][laP[it]]);
        }
    };

    const f32x4 zero = {0.f, 0.f, 0.f, 0.f};
    f32x4 acc[8][4];
#pragma unroll
    for (int i = 0; i < 8; ++i)
#pragma unroll
        for (int j = 0; j < 4; ++j) acc[i][j] = zero;

    int nst = K >> 6;                    // 4 (K=256) or 8 (K=512)
    stage(0, 0);
    for (int s = 0; s < nst; ++s) {
        __syncthreads();                 // drains vmcnt+lgkmcnt -> buf[s&1] ready
        if (s + 1 < nst) stage((s + 1) & 1, (s + 1) << 6);
        const unsigned short* Ab = As[s & 1];
        const unsigned short* Bb = Bs[s & 1];
#pragma unroll
        for (int kk = 0; kk < 2; ++kk) {
            bf16x8 af[8], bf[4];
#pragma unroll
            for (int i = 0; i < 8; ++i) {
                int r = waveM * 128 + i * 16 + l15;
                af[i] = *(const bf16x8*)&Ab[r * 64 + (((kk * 4 + quad) ^ (r & 7)) * 8)];
            }
#pragma unroll
            for (int j = 0; j < 4; ++j) {
                int r = waveN * 64 + j * 16 + l15;
                bf[j] = *(const bf16x8*)&Bb[r * 64 + (((kk * 4 + quad) ^ (r & 7)) * 8)];
            }
#pragma unroll
            for (int i = 0; i < 8; ++i)
#pragma unroll
                for (int j = 0; j < 4; ++j)
                    acc[i][j] = __builtin_amdgcn_mfma_f32_16x16x32_bf16(af[i], bf[j], acc[i][j], 0, 0, 0);
        }
    }

    const float* be = bias + (size_t)e * N;
    if (mode == 0) {
#pragma unroll
        for (int i = 0; i < 8; ++i) {
#pragma unroll
            for (int r = 0; r < 4; ++r) {
                int rl = waveM * 128 + i * 16 + quad * 4 + r;
                if (rl < valid) {
                    size_t rowOff = (size_t)(rowStart + rl) * N;
#pragma unroll
                    for (int j = 0; j < 4; ++j) {
                        int col = (int)ct * 256 + waveN * 64 + j * 16 + l15;
                        float v = acc[i][j][r] + be[col];
                        Hout[rowOff + col] = f2bf(fmaxf(v, 0.f));
                    }
                }
            }
        }
    } else {
#pragma unroll
        for (int i = 0; i < 8; ++i) {
#pragma unroll
            for (int r = 0; r < 4; ++r) {
                int rl = waveM * 128 + i * 16 + quad * 4 + r;
                if (rl < valid) {
                    int row = rowStart + rl;
                    int tok = rowTok[row];
                    float w = rowW[row];
                    float* orow = outF + (size_t)tok * DOUT;
#pragma unroll
                    for (int j = 0; j < 4; ++j) {
                        int col = (int)ct * 256 + waveN * 64 + j * 16 + l15;
                        float v = (acc[i][j][r] + be[col]) * w;
                        atomicAdd(&orow[col], v);
                    }
                }
            }
        }
    }
}

extern "C" void kernel_launch(void* const* d_in, const int* in_sizes, int n_in,
                              void* d_out, int out_size, void* d_ws, size_t ws_size,
                              hipStream_t stream) {
    const float* x   = (const float*)d_in[0];
    const float* gW1 = (const float*)d_in[1];
    const float* gb1 = (const float*)d_in[2];
    const float* gW2 = (const float*)d_in[3];
    const float* gb2 = (const float*)d_in[4];
    const float* We1 = (const float*)d_in[5];
    const float* be1 = (const float*)d_in[6];
    const float* We2 = (const float*)d_in[7];
    const float* be2 = (const float*)d_in[8];
    const float* We3 = (const float*)d_in[9];
    const float* be3 = (const float*)d_in[10];
    float* out = (float*)d_out;

    uint8_t* ws = (uint8_t*)d_ws;
    size_t off = 0;
    auto alloc = [&](size_t bytes) -> void* {
        void* p = ws + off;
        off += (bytes + 255) & ~(size_t)255;
        return p;
    };
    unsigned short* WT1 = (unsigned short*)alloc((size_t)E_ * HID * DIN * 2);   // [E][512][256]
    unsigned short* WT2 = (unsigned short*)alloc((size_t)E_ * HID * HID * 2);   // [E][512][512]
    unsigned short* WT3 = (unsigned short*)alloc((size_t)E_ * DOUT * HID * 2);  // [E][256][512]
    unsigned short* R1  = (unsigned short*)alloc((size_t)NROW * HID * 2);       // xg then h2
    unsigned short* h1  = (unsigned short*)alloc((size_t)NROW * HID * 2);
    float*  hG     = (float*)alloc((size_t)NTOK * GHID * 4);                    // gate hidden fp32
    int2*   tokE   = (int2*)alloc((size_t)NTOK * 8);
    float2* tokW   = (float2*)alloc((size_t)NTOK * 8);
    int*    rowTok = (int*)alloc((size_t)NROW * 4);
    float*  rowW   = (float*)alloc((size_t)NROW * 4);
    int*    cnt    = (int*)alloc(E_ * CNT_STRIDE * 4);
    int*    offs   = (int*)alloc(256);
    int*    fill   = (int*)alloc(256);
    int*    NT     = (int*)alloc(256);
    int2*   tab    = (int2*)alloc(TABCAP * 8);
    unsigned short* xg = R1;   // [NROW][256] bf16 (dead after gemm1)
    unsigned short* h2 = R1;   // [NROW][512] bf16 (written by gemm2)

    hipMemsetAsync(d_out, 0, (size_t)out_size * 4, stream);
    hipMemsetAsync(cnt, 0, E_ * CNT_STRIDE * 4, stream);

    k_transpose_bf16<<<dim3(DIN / 64, HID / 64, E_), 256, 0, stream>>>(We1, WT1, DIN, HID);
    k_transpose_bf16<<<dim3(HID / 64, HID / 64, E_), 256, 0, stream>>>(We2, WT2, HID, HID);
    k_transpose_bf16<<<dim3(HID / 64, DOUT / 64, E_), 256, 0, stream>>>(We3, WT3, HID, DOUT);

    k_gate1<<<NTOK / 128, 256, 0, stream>>>(x, gW1, gb1, hG);
    k_gate2<<<NTOK / 64, 256, 0, stream>>>(hG, gW2, gb2, tokE, tokW, cnt);
    k_route_setup<<<1, 64, 0, stream>>>(cnt, offs, fill, tab, NT, out);
    k_gather<<<NTOK / 256, 256, 0, stream>>>(x, tokE, tokW, offs, fill, rowTok, rowW, xg);

    k_gemm<2><<<dim3(2, TAB256), 512, 0, stream>>>(xg, WT1, be1, offs, cnt, tab, NT,
                                                   HID, DIN, 0, h1, nullptr, rowTok, rowW);
    k_gemm<2><<<dim3(2, TAB256), 512, 0, stream>>>(h1, WT2, be2, offs, cnt, tab, NT,
                                                   HID, HID, 0, h2, nullptr, rowTok, rowW);
    k_gemm<1><<<dim3(1, TAB256), 512, 0, stream>>>(h2, WT3, be3, offs, cnt, tab, NT,
                                                   DOUT, HID, 1, nullptr, out, rowTok, rowW);
}

// Round 12
// 423.406 us; speedup vs baseline: 1.1216x; 1.1216x over previous
//
#include <hip/hip_runtime.h>
#include <stdint.h>

#define E_ 8
#define DIN 256
#define DOUT 256
#define HID 512
#define GHID 128
#define NTOK 32768
#define NROW (NTOK * 2)
#define TABCAP 520
#define CNT_STRIDE 32

typedef float f32x4 __attribute__((ext_vector_type(4)));
typedef short bf16x8 __attribute__((ext_vector_type(8)));

// fp32 -> bf16 round-to-nearest-even
__device__ __forceinline__ unsigned short f2bf(float f) {
    unsigned int u = __float_as_uint(f);
    u += 0x7FFFu + ((u >> 16) & 1u);
    return (unsigned short)(u >> 16);
}

// async global->LDS, 16B per lane; LDS base must be wave-uniform (HW adds lane*16)
__device__ __forceinline__ void gload_lds16(const void* g, void* l) {
    __builtin_amdgcn_global_load_lds(
        (const __attribute__((address_space(1))) unsigned int*)g,
        (__attribute__((address_space(3))) unsigned int*)l, 16, 0, 0);
}

// ---------- weight transpose + bf16 convert: W[e][K][N] -> WT[e][N][K] ----------
__global__ __launch_bounds__(256) void k_transpose_bf16(
    const float* __restrict__ src, unsigned short* __restrict__ dst, int K, int N) {
    __shared__ float tile[64][65];
    int e = blockIdx.z;
    int k0 = blockIdx.x * 64, n0 = blockIdx.y * 64;
    const float* s = src + (size_t)e * K * N;
    unsigned short* d = dst + (size_t)e * N * K;
    int col = threadIdx.x & 63, ri = threadIdx.x >> 6;
#pragma unroll
    for (int it = 0; it < 16; ++it) {
        int row = it * 4 + ri;
        tile[row][col] = s[(size_t)(k0 + row) * N + n0 + col];
    }
    __syncthreads();
#pragma unroll
    for (int it = 0; it < 16; ++it) {
        int nrow = it * 4 + ri;
        d[(size_t)(n0 + nrow) * K + k0 + col] = f2bf(tile[col][nrow]);
    }
}

// ---------- gate layer 1: h = relu(x @ gW1 + gb1), fp32, register-blocked ----------
__global__ __launch_bounds__(256) void k_gate1(
    const float* __restrict__ x, const float* __restrict__ gW1,
    const float* __restrict__ gb1, float* __restrict__ hG) {
    __shared__ float xT[32][132];   // [kk][tok]
    __shared__ float ws[32][132];   // [kk][hid] (128 used)
    int t = threadIdx.x;
    int tokBase = blockIdx.x * 128;
    int tx = t & 15, ty = t >> 4;
    float acc[8][8];
#pragma unroll
    for (int i = 0; i < 8; ++i)
#pragma unroll
        for (int j = 0; j < 8; ++j) acc[i][j] = 0.f;

    int stok = t >> 1;
    int skh = (t & 1) * 16;
    int wkk = t >> 3;
    int wh = (t & 7) * 16;

    for (int k0 = 0; k0 < DIN; k0 += 32) {
        const float* xr = x + (size_t)(tokBase + stok) * DIN + k0 + skh;
        float4 a0 = ((const float4*)xr)[0];
        float4 a1 = ((const float4*)xr)[1];
        float4 a2 = ((const float4*)xr)[2];
        float4 a3 = ((const float4*)xr)[3];
        xT[skh + 0][stok] = a0.x;  xT[skh + 1][stok] = a0.y;
        xT[skh + 2][stok] = a0.z;  xT[skh + 3][stok] = a0.w;
        xT[skh + 4][stok] = a1.x;  xT[skh + 5][stok] = a1.y;
        xT[skh + 6][stok] = a1.z;  xT[skh + 7][stok] = a1.w;
        xT[skh + 8][stok] = a2.x;  xT[skh + 9][stok] = a2.y;
        xT[skh + 10][stok] = a2.z; xT[skh + 11][stok] = a2.w;
        xT[skh + 12][stok] = a3.x; xT[skh + 13][stok] = a3.y;
        xT[skh + 14][stok] = a3.z; xT[skh + 15][stok] = a3.w;
        const float* wr = gW1 + (size_t)(k0 + wkk) * GHID + wh;
        *(float4*)&ws[wkk][wh + 0]  = ((const float4*)wr)[0];
        *(float4*)&ws[wkk][wh + 4]  = ((const float4*)wr)[1];
        *(float4*)&ws[wkk][wh + 8]  = ((const float4*)wr)[2];
        *(float4*)&ws[wkk][wh + 12] = ((const float4*)wr)[3];
        __syncthreads();
#pragma unroll 4
        for (int kk = 0; kk < 32; ++kk) {
            f32x4 wv0 = *(const f32x4*)&ws[kk][tx * 8];
            f32x4 wv1 = *(const f32x4*)&ws[kk][tx * 8 + 4];
            f32x4 xv0 = *(const f32x4*)&xT[kk][ty * 8];
            f32x4 xv1 = *(const f32x4*)&xT[kk][ty * 8 + 4];
            float xs[8] = {xv0.x, xv0.y, xv0.z, xv0.w, xv1.x, xv1.y, xv1.z, xv1.w};
            float wsv[8] = {wv0.x, wv0.y, wv0.z, wv0.w, wv1.x, wv1.y, wv1.z, wv1.w};
#pragma unroll
            for (int i = 0; i < 8; ++i)
#pragma unroll
                for (int j = 0; j < 8; ++j) acc[i][j] += xs[i] * wsv[j];
        }
        __syncthreads();
    }
    float4 b0 = *(const float4*)&gb1[tx * 8];
    float4 b1 = *(const float4*)&gb1[tx * 8 + 4];
#pragma unroll
    for (int i = 0; i < 8; ++i) {
        int tok = tokBase + ty * 8 + i;
        float4 o0, o1;
        o0.x = fmaxf(acc[i][0] + b0.x, 0.f); o0.y = fmaxf(acc[i][1] + b0.y, 0.f);
        o0.z = fmaxf(acc[i][2] + b0.z, 0.f); o0.w = fmaxf(acc[i][3] + b0.w, 0.f);
        o1.x = fmaxf(acc[i][4] + b1.x, 0.f); o1.y = fmaxf(acc[i][5] + b1.y, 0.f);
        o1.z = fmaxf(acc[i][6] + b1.z, 0.f); o1.w = fmaxf(acc[i][7] + b1.w, 0.f);
        float* hr = &hG[(size_t)tok * GHID + tx * 8];
        ((float4*)hr)[0] = o0;
        ((float4*)hr)[1] = o1;
    }
}

// ---------- gate layer 2 + top2 + counts ----------
__global__ __launch_bounds__(256) void k_gate2(
    const float* __restrict__ hG, const float* __restrict__ gW2,
    const float* __restrict__ gb2, int2* __restrict__ tokE,
    float2* __restrict__ tokW, int* __restrict__ cnt) {
    __shared__ float hs[64][132];
    __shared__ float wg[GHID * E_];
    __shared__ int lcnt[E_];
    int t = threadIdx.x;
    int tokBase = blockIdx.x * 64;
#pragma unroll
    for (int i = 0; i < 4; ++i) wg[i * 256 + t] = gW2[i * 256 + t];
    if (t < E_) lcnt[t] = 0;
#pragma unroll
    for (int it = 0; it < 8; ++it) {
        int idx = it * 256 + t;
        int tok = idx >> 5, col = (idx & 31) * 4;
        float4 v = *(const float4*)&hG[(size_t)(tokBase + tok) * GHID + col];
        *(float4*)&hs[tok][col] = v;
    }
    __syncthreads();
    int tok = t >> 2, part = t & 3;
    float s[8];
#pragma unroll
    for (int e = 0; e < E_; ++e) s[e] = 0.f;
    const float* hr = &hs[tok][part * 32];
#pragma unroll 2
    for (int jq = 0; jq < 8; ++jq) {
        f32x4 hv = *(const f32x4*)&hr[jq * 4];
#pragma unroll
        for (int j = 0; j < 4; ++j) {
            float h = hv[j];
            int hidx = part * 32 + jq * 4 + j;
            f32x4 w0 = *(const f32x4*)&wg[hidx * 8];
            f32x4 w1 = *(const f32x4*)&wg[hidx * 8 + 4];
            s[0] += h * w0.x; s[1] += h * w0.y; s[2] += h * w0.z; s[3] += h * w0.w;
            s[4] += h * w1.x; s[5] += h * w1.y; s[6] += h * w1.z; s[7] += h * w1.w;
        }
    }
#pragma unroll
    for (int e = 0; e < E_; ++e) {
        s[e] += __shfl_xor(s[e], 1);
        s[e] += __shfl_xor(s[e], 2);
    }
    if (part == 0) {
        float l[8];
#pragma unroll
        for (int e = 0; e < E_; ++e) l[e] = s[e] + gb2[e];
        int i1 = 0; float b1v = l[0];
#pragma unroll
        for (int e = 1; e < E_; ++e) if (l[e] > b1v) { b1v = l[e]; i1 = e; }
        int i2 = -1; float b2v = -3.4e38f;
#pragma unroll
        for (int e = 0; e < E_; ++e) if (e != i1 && l[e] > b2v) { b2v = l[e]; i2 = e; }
        float mm = fmaxf(b1v, b2v);
        float p1 = expf(b1v - mm), p2 = expf(b2v - mm);
        float inv = 1.f / (p1 + p2);
        int gtok = tokBase + tok;
        tokE[gtok] = make_int2(i1, i2);
        tokW[gtok] = make_float2(p1 * inv, p2 * inv);
        atomicAdd(&lcnt[i1], 1);
        atomicAdd(&lcnt[i2], 1);
    }
    __syncthreads();
    if (t < E_) atomicAdd(&cnt[t * CNT_STRIDE], lcnt[t]);
}

// ---------- prefix offsets, tile work table (128-row tiles), aux outputs ----------
// Tab order: (k,e) lexicographic round-robin -> tab[i].expert == i%8 while all
// experts still have tiles; with the k_gemm remap (xcd = tIdx%8) this pins each
// expert to one XCD L2. All per-expert arrays unrolled -> registers.
__global__ void k_route_setup(const int* __restrict__ cnt, int* __restrict__ offs,
                              int* __restrict__ fill, int2* __restrict__ tab,
                              int* __restrict__ NT, float* __restrict__ outTail) {
    int t = threadIdx.x;   // 64 threads
    int c[E_], nt[E_];
#pragma unroll
    for (int e = 0; e < E_; ++e) {
        c[e] = cnt[e * CNT_STRIDE];
        nt[e] = (c[e] + 127) >> 7;
    }
    if (t == 0) {
        int off = 0, ntp = 0;
        float bl = 0.f;
#pragma unroll
        for (int e = 0; e < E_; ++e) {
            offs[e] = off; off += c[e];
            fill[e] = 0;
            ntp += nt[e];
            float u = (float)c[e] / 32768.f;
            outTail[8388609 + e] = u;
            float dd = u - 0.125f;
            bl += dd * dd;
        }
        outTail[8388608] = bl * (0.01f / 8.f);
        *NT = ntp;
    }
    int maxnt = 0;
#pragma unroll
    for (int e = 0; e < E_; ++e) maxnt = max(maxnt, nt[e]);
    for (int k = t; k < maxnt; k += 64) {
        int p = 0;
#pragma unroll
        for (int e = 0; e < E_; ++e) p += min(nt[e], k);
#pragma unroll
        for (int e = 0; e < E_; ++e) {
            if (k < nt[e]) {
                tab[p] = make_int2(e, k);
                ++p;
            }
        }
    }
}

// ---------- gather: assign rows, record token/weight, copy x rows to bf16 ----------
__global__ __launch_bounds__(256) void k_gather(
    const float* __restrict__ x, const int2* __restrict__ tokE,
    const float2* __restrict__ tokW, const int* __restrict__ offs,
    int* __restrict__ fill, int* __restrict__ rowTok, float* __restrict__ rowW,
    unsigned short* __restrict__ xg) {
    __shared__ int lc[E_], lbase[E_], lfill[E_];
    __shared__ int srow[512];
    int t = threadIdx.x;
    int tokBase = blockIdx.x * 256;
    if (t < E_) { lc[t] = 0; lfill[t] = 0; }
    __syncthreads();
    for (int s = t; s < 512; s += 256) {
        int token = tokBase + (s >> 1);
        int2 ee = tokE[token];
        int e = (s & 1) ? ee.y : ee.x;
        atomicAdd(&lc[e], 1);
    }
    __syncthreads();
    if (t < E_) lbase[t] = atomicAdd(&fill[t], lc[t]);
    __syncthreads();
    for (int s = t; s < 512; s += 256) {
        int token = tokBase + (s >> 1);
        int2 ee = tokE[token];
        float2 wv = tokW[token];
        int e; float w;
        if (s & 1) { e = ee.y; w = wv.y; } else { e = ee.x; w = wv.x; }
        int r = atomicAdd(&lfill[e], 1);
        int row = offs[e] + lbase[e] + r;
        srow[s] = row;
        rowTok[row] = token;
        rowW[row] = w;
    }
    __syncthreads();
    int wid = t >> 6, lane = t & 63;
    for (int s = wid; s < 512; s += 4) {
        int row = srow[s];
        int token = tokBase + (s >> 1);
        float4 v = ((const float4*)x)[(size_t)token * 64 + lane];
        ushort4 o;
        o.x = f2bf(v.x); o.y = f2bf(v.y); o.z = f2bf(v.z); o.w = f2bf(v.w);
        ((ushort4*)xg)[(size_t)row * 64 + lane] = o;
    }
}

// ---------- grouped GEMM, 128x256 tile, 8 waves, BK=32, 2-buf LDS ----------
// Traffic-first at preserved residency: cross-round data shows the wall is
// sustained load-service BW (period tracks staged bytes/CU; 83% idle waiting).
// BN=256 halves NCT -> A-panels read half as often; per-output staged bytes
// -33% vs R10, per-step MFMA/wave 2x (amortization), while keeping the
// R10-proven 16 waves/CU: acc[4][4]=64 AGPR + ~45 VGPR < 128-reg cliff ->
// 4 waves/SIMD; LDS 2x24KB = 48KB (same footprint R10 ran 2 blocks/CU at).
// 8-chunk... chunk-XOR swizzle (R8-verified conflicts=0): source chunk
// p^((row>>1)&3) within the row's 64B window, read chunk quad^((l15>>1)&3).
// XCD remap: xcd = flat%8 = tIdx%8 + expert-interleaved tab pins experts to XCDs.
// mode 0: Hout = relu(acc+bias) bf16; mode 1: atomicAdd(out, (acc+bias)*rowW)
template <int NCT>
__global__ __launch_bounds__(512, 4) void k_gemm(
    const unsigned short* __restrict__ A, const unsigned short* __restrict__ BT,
    const float* __restrict__ bias, const int* __restrict__ offs,
    const int* __restrict__ cnt, const int2* __restrict__ tab,
    const int* __restrict__ NT, int N, int K, int mode,
    unsigned short* __restrict__ Hout, float* __restrict__ outF,
    const int* __restrict__ rowTok, const float* __restrict__ rowW) {
    __shared__ __align__(16) unsigned short As[2][128 * 32];  // 8 KB per buf
    __shared__ __align__(16) unsigned short Bs[2][256 * 32];  // 16 KB per buf

    // flat = xcd + 8*(ct + NCT*qq) -> (ct, tIdx = 8*qq + xcd). Bijection for
    // gridDim.y = TABCAP = 520 = 65*8.
    unsigned flat = blockIdx.x + (unsigned)NCT * blockIdx.y;
    unsigned xcd = flat % 8u;
    unsigned q = flat / 8u;
    unsigned ct = q % (unsigned)NCT;
    unsigned tIdx = (q / (unsigned)NCT) * 8u + xcd;

    if (tIdx >= (unsigned)*NT || tIdx >= (unsigned)TABCAP) return;
    int2 ent = tab[tIdx];
    int e = ent.x, rt = ent.y;
    int cntE = cnt[e * CNT_STRIDE];
    int rowStart = offs[e] + rt * 128;
    int valid = cntE - rt * 128;
    if (valid > 128) valid = 128;

    int t = threadIdx.x;
    int lane = t & 63, wid = t >> 6;          // 8 waves
    int quad = lane >> 4, l15 = lane & 15;
    int waveM = wid >> 2, waveN = wid & 3;    // 2M x 4N: wave owns 64 rows x 64 cols

    const unsigned short* Ablk = A + (size_t)rowStart * K;
    const unsigned short* Bblk = BT + ((size_t)e * N + (size_t)ct * 256) * K;

    // staging per step: A 128x32 (512 slots of 16B, 1/thread) + B 256x32
    // (1024 slots, 2/thread). slot -> row = slot>>2, pos p = slot&3, source
    // chunk = p ^ ((row>>1)&3) (involution, same 64B window). LDS linear
    // [row][32]: slot s lands at s*16B; wave-uniform base + HW lane*16 (G21).
    int arow = t >> 2, ap = t & 3;
    int achk = ap ^ ((arow >> 1) & 3);
    int ar = min(arow, valid - 1);
    const unsigned short* ga = Ablk + (size_t)ar * K + achk * 8;
    int brow0 = t >> 2;                 // slots t: rows 0..127
    int bchk0 = (t & 3) ^ ((brow0 >> 1) & 3);
    int brow1 = brow0 + 128;            // slots t+512: rows 128..255
    int bchk1 = (t & 3) ^ ((brow1 >> 1) & 3);
    const unsigned short* gb0 = Bblk + (size_t)brow0 * K + bchk0 * 8;
    const unsigned short* gb1 = Bblk + (size_t)brow1 * K + bchk1 * 8;
    int laA = wid * 512;                // elems
    int laB0 = wid * 512;
    int laB1 = 4096 + wid * 512;

    auto stage = [&](int b, int kt) {
        gload_lds16(ga + kt, &As[b][laA]);
        gload_lds16(gb0 + kt, &Bs[b][laB0]);
        gload_lds16(gb1 + kt, &Bs[b][laB1]);
    };

    const f32x4 zero = {0.f, 0.f, 0.f, 0.f};
    f32x4 acc[4][4];
#pragma unroll
    for (int i = 0; i < 4; ++i)
#pragma unroll
        for (int j = 0; j < 4; ++j) acc[i][j] = zero;

    int xq = quad ^ ((l15 >> 1) & 3);   // swizzled read chunk
    int nst = K >> 5;                    // 8 (K=256) or 16 (K=512)
    stage(0, 0);
    for (int s = 0; s < nst; ++s) {
        __syncthreads();                 // drains vmcnt -> buf[s&1] ready
        if (s + 1 < nst) stage((s + 1) & 1, (s + 1) << 5);
        const unsigned short* Ab = As[s & 1];
        const unsigned short* Bb = Bs[s & 1];
        bf16x8 af[4], bf[4];
#pragma unroll
        for (int i = 0; i < 4; ++i)
            af[i] = *(const bf16x8*)&Ab[(waveM * 64 + i * 16 + l15) * 32 + xq * 8];
#pragma unroll
        for (int j = 0; j < 4; ++j)
            bf[j] = *(const bf16x8*)&Bb[(waveN * 64 + j * 16 + l15) * 32 + xq * 8];
#pragma unroll
        for (int i = 0; i < 4; ++i)
#pragma unroll
            for (int j = 0; j < 4; ++j)
                acc[i][j] = __builtin_amdgcn_mfma_f32_16x16x32_bf16(af[i], bf[j], acc[i][j], 0, 0, 0);
    }

    const float* be = bias + (size_t)e * N;
    if (mode == 0) {
#pragma unroll
        for (int i = 0; i < 4; ++i) {
#pragma unroll
            for (int r = 0; r < 4; ++r) {
                int rl = waveM * 64 + i * 16 + quad * 4 + r;
                if (rl < valid) {
                    size_t rowOff = (size_t)(rowStart + rl) * N;
#pragma unroll
                    for (int j = 0; j < 4; ++j) {
                        int col = (int)ct * 256 + waveN * 64 + j * 16 + l15;
                        float v = acc[i][j][r] + be[col];
                        Hout[rowOff + col] = f2bf(fmaxf(v, 0.f));
                    }
                }
            }
        }
    } else {
#pragma unroll
        for (int i = 0; i < 4; ++i) {
#pragma unroll
            for (int r = 0; r < 4; ++r) {
                int rl = waveM * 64 + i * 16 + quad * 4 + r;
                if (rl < valid) {
                    int row = rowStart + rl;
                    int tok = rowTok[row];
                    float w = rowW[row];
                    float* orow = outF + (size_t)tok * DOUT;
#pragma unroll
                    for (int j = 0; j < 4; ++j) {
                        int col = (int)ct * 256 + waveN * 64 + j * 16 + l15;
                        float v = (acc[i][j][r] + be[col]) * w;
                        atomicAdd(&orow[col], v);
                    }
                }
            }
        }
    }
}

extern "C" void kernel_launch(void* const* d_in, const int* in_sizes, int n_in,
                              void* d_out, int out_size, void* d_ws, size_t ws_size,
                              hipStream_t stream) {
    const float* x   = (const float*)d_in[0];
    const float* gW1 = (const float*)d_in[1];
    const float* gb1 = (const float*)d_in[2];
    const float* gW2 = (const float*)d_in[3];
    const float* gb2 = (const float*)d_in[4];
    const float* We1 = (const float*)d_in[5];
    const float* be1 = (const float*)d_in[6];
    const float* We2 = (const float*)d_in[7];
    const float* be2 = (const float*)d_in[8];
    const float* We3 = (const float*)d_in[9];
    const float* be3 = (const float*)d_in[10];
    float* out = (float*)d_out;

    uint8_t* ws = (uint8_t*)d_ws;
    size_t off = 0;
    auto alloc = [&](size_t bytes) -> void* {
        void* p = ws + off;
        off += (bytes + 255) & ~(size_t)255;
        return p;
    };
    unsigned short* WT1 = (unsigned short*)alloc((size_t)E_ * HID * DIN * 2);   // [E][512][256]
    unsigned short* WT2 = (unsigned short*)alloc((size_t)E_ * HID * HID * 2);   // [E][512][512]
    unsigned short* WT3 = (unsigned short*)alloc((size_t)E_ * DOUT * HID * 2);  // [E][256][512]
    unsigned short* R1  = (unsigned short*)alloc((size_t)NROW * HID * 2);       // xg then h2
    unsigned short* h1  = (unsigned short*)alloc((size_t)NROW * HID * 2);
    float*  hG     = (float*)alloc((size_t)NTOK * GHID * 4);                    // gate hidden fp32
    int2*   tokE   = (int2*)alloc((size_t)NTOK * 8);
    float2* tokW   = (float2*)alloc((size_t)NTOK * 8);
    int*    rowTok = (int*)alloc((size_t)NROW * 4);
    float*  rowW   = (float*)alloc((size_t)NROW * 4);
    int*    cnt    = (int*)alloc(E_ * CNT_STRIDE * 4);
    int*    offs   = (int*)alloc(256);
    int*    fill   = (int*)alloc(256);
    int*    NT     = (int*)alloc(256);
    int2*   tab    = (int2*)alloc(TABCAP * 8);
    unsigned short* xg = R1;   // [NROW][256] bf16 (dead after gemm1)
    unsigned short* h2 = R1;   // [NROW][512] bf16 (written by gemm2)

    hipMemsetAsync(d_out, 0, (size_t)out_size * 4, stream);
    hipMemsetAsync(cnt, 0, E_ * CNT_STRIDE * 4, stream);

    k_transpose_bf16<<<dim3(DIN / 64, HID / 64, E_), 256, 0, stream>>>(We1, WT1, DIN, HID);
    k_transpose_bf16<<<dim3(HID / 64, HID / 64, E_), 256, 0, stream>>>(We2, WT2, HID, HID);
    k_transpose_bf16<<<dim3(HID / 64, DOUT / 64, E_), 256, 0, stream>>>(We3, WT3, HID, DOUT);

    k_gate1<<<NTOK / 128, 256, 0, stream>>>(x, gW1, gb1, hG);
    k_gate2<<<NTOK / 64, 256, 0, stream>>>(hG, gW2, gb2, tokE, tokW, cnt);
    k_route_setup<<<1, 64, 0, stream>>>(cnt, offs, fill, tab, NT, out);
    k_gather<<<NTOK / 256, 256, 0, stream>>>(x, tokE, tokW, offs, fill, rowTok, rowW, xg);

    k_gemm<2><<<dim3(2, TABCAP), 512, 0, stream>>>(xg, WT1, be1, offs, cnt, tab, NT,
                                                   HID, DIN, 0, h1, nullptr, rowTok, rowW);
    k_gemm<2><<<dim3(2, TABCAP), 512, 0, stream>>>(h1, WT2, be2, offs, cnt, tab, NT,
                                                   HID, HID, 0, h2, nullptr, rowTok, rowW);
    k_gemm<1><<<dim3(1, TABCAP), 512, 0, stream>>>(h2, WT3, be3, offs, cnt, tab, NT,
                                                   DOUT, HID, 1, nullptr, out, rowTok, rowW);
}

// Round 13
// 355.738 us; speedup vs baseline: 1.3349x; 1.1902x over previous
//
#include <hip/hip_runtime.h>
#include <stdint.h>

#define E_ 8
#define DIN 256
#define DOUT 256
#define HID 512
#define GHID 128
#define NTOK 32768
#define NROW (NTOK * 2)
#define TABCAP 520
#define CNT_STRIDE 32

typedef float f32x4 __attribute__((ext_vector_type(4)));
typedef short bf16x8 __attribute__((ext_vector_type(8)));

// fp32 -> bf16 round-to-nearest-even
__device__ __forceinline__ unsigned short f2bf(float f) {
    unsigned int u = __float_as_uint(f);
    u += 0x7FFFu + ((u >> 16) & 1u);
    return (unsigned short)(u >> 16);
}

// async global->LDS, 16B per lane; LDS base must be wave-uniform (HW adds lane*16)
__device__ __forceinline__ void gload_lds16(const void* g, void* l) {
    __builtin_amdgcn_global_load_lds(
        (const __attribute__((address_space(1))) unsigned int*)g,
        (__attribute__((address_space(3))) unsigned int*)l, 16, 0, 0);
}

// ---------- weight transpose + bf16 convert: W[e][K][N] -> WT[e][N][K] ----------
__global__ __launch_bounds__(256) void k_transpose_bf16(
    const float* __restrict__ src, unsigned short* __restrict__ dst, int K, int N) {
    __shared__ float tile[64][65];
    int e = blockIdx.z;
    int k0 = blockIdx.x * 64, n0 = blockIdx.y * 64;
    const float* s = src + (size_t)e * K * N;
    unsigned short* d = dst + (size_t)e * N * K;
    int col = threadIdx.x & 63, ri = threadIdx.x >> 6;
#pragma unroll
    for (int it = 0; it < 16; ++it) {
        int row = it * 4 + ri;
        tile[row][col] = s[(size_t)(k0 + row) * N + n0 + col];
    }
    __syncthreads();
#pragma unroll
    for (int it = 0; it < 16; ++it) {
        int nrow = it * 4 + ri;
        d[(size_t)(n0 + nrow) * K + k0 + col] = f2bf(tile[col][nrow]);
    }
}

// ---------- gate layer 1: h = relu(x @ gW1 + gb1), fp32, register-blocked ----------
__global__ __launch_bounds__(256) void k_gate1(
    const float* __restrict__ x, const float* __restrict__ gW1,
    const float* __restrict__ gb1, float* __restrict__ hG) {
    __shared__ float xT[32][132];   // [kk][tok]
    __shared__ float ws[32][132];   // [kk][hid] (128 used)
    int t = threadIdx.x;
    int tokBase = blockIdx.x * 128;
    int tx = t & 15, ty = t >> 4;
    float acc[8][8];
#pragma unroll
    for (int i = 0; i < 8; ++i)
#pragma unroll
        for (int j = 0; j < 8; ++j) acc[i][j] = 0.f;

    int stok = t >> 1;
    int skh = (t & 1) * 16;
    int wkk = t >> 3;
    int wh = (t & 7) * 16;

    for (int k0 = 0; k0 < DIN; k0 += 32) {
        const float* xr = x + (size_t)(tokBase + stok) * DIN + k0 + skh;
        float4 a0 = ((const float4*)xr)[0];
        float4 a1 = ((const float4*)xr)[1];
        float4 a2 = ((const float4*)xr)[2];
        float4 a3 = ((const float4*)xr)[3];
        xT[skh + 0][stok] = a0.x;  xT[skh + 1][stok] = a0.y;
        xT[skh + 2][stok] = a0.z;  xT[skh + 3][stok] = a0.w;
        xT[skh + 4][stok] = a1.x;  xT[skh + 5][stok] = a1.y;
        xT[skh + 6][stok] = a1.z;  xT[skh + 7][stok] = a1.w;
        xT[skh + 8][stok] = a2.x;  xT[skh + 9][stok] = a2.y;
        xT[skh + 10][stok] = a2.z; xT[skh + 11][stok] = a2.w;
        xT[skh + 12][stok] = a3.x; xT[skh + 13][stok] = a3.y;
        xT[skh + 14][stok] = a3.z; xT[skh + 15][stok] = a3.w;
        const float* wr = gW1 + (size_t)(k0 + wkk) * GHID + wh;
        *(float4*)&ws[wkk][wh + 0]  = ((const float4*)wr)[0];
        *(float4*)&ws[wkk][wh + 4]  = ((const float4*)wr)[1];
        *(float4*)&ws[wkk][wh + 8]  = ((const float4*)wr)[2];
        *(float4*)&ws[wkk][wh + 12] = ((const float4*)wr)[3];
        __syncthreads();
#pragma unroll 4
        for (int kk = 0; kk < 32; ++kk) {
            f32x4 wv0 = *(const f32x4*)&ws[kk][tx * 8];
            f32x4 wv1 = *(const f32x4*)&ws[kk][tx * 8 + 4];
            f32x4 xv0 = *(const f32x4*)&xT[kk][ty * 8];
            f32x4 xv1 = *(const f32x4*)&xT[kk][ty * 8 + 4];
            float xs[8] = {xv0.x, xv0.y, xv0.z, xv0.w, xv1.x, xv1.y, xv1.z, xv1.w};
            float wsv[8] = {wv0.x, wv0.y, wv0.z, wv0.w, wv1.x, wv1.y, wv1.z, wv1.w};
#pragma unroll
            for (int i = 0; i < 8; ++i)
#pragma unroll
                for (int j = 0; j < 8; ++j) acc[i][j] += xs[i] * wsv[j];
        }
        __syncthreads();
    }
    float4 b0 = *(const float4*)&gb1[tx * 8];
    float4 b1 = *(const float4*)&gb1[tx * 8 + 4];
#pragma unroll
    for (int i = 0; i < 8; ++i) {
        int tok = tokBase + ty * 8 + i;
        float4 o0, o1;
        o0.x = fmaxf(acc[i][0] + b0.x, 0.f); o0.y = fmaxf(acc[i][1] + b0.y, 0.f);
        o0.z = fmaxf(acc[i][2] + b0.z, 0.f); o0.w = fmaxf(acc[i][3] + b0.w, 0.f);
        o1.x = fmaxf(acc[i][4] + b1.x, 0.f); o1.y = fmaxf(acc[i][5] + b1.y, 0.f);
        o1.z = fmaxf(acc[i][6] + b1.z, 0.f); o1.w = fmaxf(acc[i][7] + b1.w, 0.f);
        float* hr = &hG[(size_t)tok * GHID + tx * 8];
        ((float4*)hr)[0] = o0;
        ((float4*)hr)[1] = o1;
    }
}

// ---------- gate layer 2 + top2 + counts ----------
__global__ __launch_bounds__(256) void k_gate2(
    const float* __restrict__ hG, const float* __restrict__ gW2,
    const float* __restrict__ gb2, int2* __restrict__ tokE,
    float2* __restrict__ tokW, int* __restrict__ cnt) {
    __shared__ float hs[64][132];
    __shared__ float wg[GHID * E_];
    __shared__ int lcnt[E_];
    int t = threadIdx.x;
    int tokBase = blockIdx.x * 64;
#pragma unroll
    for (int i = 0; i < 4; ++i) wg[i * 256 + t] = gW2[i * 256 + t];
    if (t < E_) lcnt[t] = 0;
#pragma unroll
    for (int it = 0; it < 8; ++it) {
        int idx = it * 256 + t;
        int tok = idx >> 5, col = (idx & 31) * 4;
        float4 v = *(const float4*)&hG[(size_t)(tokBase + tok) * GHID + col];
        *(float4*)&hs[tok][col] = v;
    }
    __syncthreads();
    int tok = t >> 2, part = t & 3;
    float s[8];
#pragma unroll
    for (int e = 0; e < E_; ++e) s[e] = 0.f;
    const float* hr = &hs[tok][part * 32];
#pragma unroll 2
    for (int jq = 0; jq < 8; ++jq) {
        f32x4 hv = *(const f32x4*)&hr[jq * 4];
#pragma unroll
        for (int j = 0; j < 4; ++j) {
            float h = hv[j];
            int hidx = part * 32 + jq * 4 + j;
            f32x4 w0 = *(const f32x4*)&wg[hidx * 8];
            f32x4 w1 = *(const f32x4*)&wg[hidx * 8 + 4];
            s[0] += h * w0.x; s[1] += h * w0.y; s[2] += h * w0.z; s[3] += h * w0.w;
            s[4] += h * w1.x; s[5] += h * w1.y; s[6] += h * w1.z; s[7] += h * w1.w;
        }
    }
#pragma unroll
    for (int e = 0; e < E_; ++e) {
        s[e] += __shfl_xor(s[e], 1);
        s[e] += __shfl_xor(s[e], 2);
    }
    if (part == 0) {
        float l[8];
#pragma unroll
        for (int e = 0; e < E_; ++e) l[e] = s[e] + gb2[e];
        int i1 = 0; float b1v = l[0];
#pragma unroll
        for (int e = 1; e < E_; ++e) if (l[e] > b1v) { b1v = l[e]; i1 = e; }
        int i2 = -1; float b2v = -3.4e38f;
#pragma unroll
        for (int e = 0; e < E_; ++e) if (e != i1 && l[e] > b2v) { b2v = l[e]; i2 = e; }
        float mm = fmaxf(b1v, b2v);
        float p1 = expf(b1v - mm), p2 = expf(b2v - mm);
        float inv = 1.f / (p1 + p2);
        int gtok = tokBase + tok;
        tokE[gtok] = make_int2(i1, i2);
        tokW[gtok] = make_float2(p1 * inv, p2 * inv);
        atomicAdd(&lcnt[i1], 1);
        atomicAdd(&lcnt[i2], 1);
    }
    __syncthreads();
    if (t < E_) atomicAdd(&cnt[t * CNT_STRIDE], lcnt[t]);
}

// ---------- prefix offsets, tile work table, aux outputs (parallel fill) ----------
// Tab order: (k,e) lexicographic round-robin -> tab[i].expert == i%8 while all
// experts still have tiles; combined with the k_gemm remap (xcd = tIdx%8) this
// pins each expert to one XCD L2. All per-expert arrays unrolled -> registers.
__global__ void k_route_setup(const int* __restrict__ cnt, int* __restrict__ offs,
                              int* __restrict__ fill, int2* __restrict__ tab,
                              int* __restrict__ NT, float* __restrict__ outTail) {
    int t = threadIdx.x;   // 64 threads
    int c[E_], nt[E_];
#pragma unroll
    for (int e = 0; e < E_; ++e) {
        c[e] = cnt[e * CNT_STRIDE];
        nt[e] = (c[e] + 127) >> 7;
    }
    if (t == 0) {
        int off = 0, ntp = 0;
        float bl = 0.f;
#pragma unroll
        for (int e = 0; e < E_; ++e) {
            offs[e] = off; off += c[e];
            fill[e] = 0;
            ntp += nt[e];
            float u = (float)c[e] / 32768.f;
            outTail[8388609 + e] = u;
            float dd = u - 0.125f;
            bl += dd * dd;
        }
        outTail[8388608] = bl * (0.01f / 8.f);
        *NT = ntp;
    }
    int maxnt = 0;
#pragma unroll
    for (int e = 0; e < E_; ++e) maxnt = max(maxnt, nt[e]);
    for (int k = t; k < maxnt; k += 64) {
        int p = 0;
#pragma unroll
        for (int e = 0; e < E_; ++e) p += min(nt[e], k);
#pragma unroll
        for (int e = 0; e < E_; ++e) {
            if (k < nt[e]) {
                tab[p] = make_int2(e, k);
                ++p;
            }
        }
    }
}

// ---------- gather: assign rows, record token/weight + tokRow, copy x to bf16 ----------
__global__ __launch_bounds__(256) void k_gather(
    const float* __restrict__ x, const int2* __restrict__ tokE,
    const float2* __restrict__ tokW, const int* __restrict__ offs,
    int* __restrict__ fill, int* __restrict__ rowTok, float* __restrict__ rowW,
    int2* __restrict__ tokRow, unsigned short* __restrict__ xg) {
    __shared__ int lc[E_], lbase[E_], lfill[E_];
    __shared__ int srow[512];
    int t = threadIdx.x;
    int tokBase = blockIdx.x * 256;
    if (t < E_) { lc[t] = 0; lfill[t] = 0; }
    __syncthreads();
    for (int s = t; s < 512; s += 256) {
        int token = tokBase + (s >> 1);
        int2 ee = tokE[token];
        int e = (s & 1) ? ee.y : ee.x;
        atomicAdd(&lc[e], 1);
    }
    __syncthreads();
    if (t < E_) lbase[t] = atomicAdd(&fill[t], lc[t]);
    __syncthreads();
    for (int s = t; s < 512; s += 256) {
        int token = tokBase + (s >> 1);
        int2 ee = tokE[token];
        float2 wv = tokW[token];
        int e; float w;
        if (s & 1) { e = ee.y; w = wv.y; } else { e = ee.x; w = wv.x; }
        int r = atomicAdd(&lfill[e], 1);
        int row = offs[e] + lbase[e] + r;
        srow[s] = row;
        rowTok[row] = token;
        rowW[row] = w;
        // record token -> (row0,row1); two disjoint 4B component writes
        ((int*)&tokRow[token])[s & 1] = row;
    }
    __syncthreads();
    int wid = t >> 6, lane = t & 63;
    for (int s = wid; s < 512; s += 4) {
        int row = srow[s];
        int token = tokBase + (s >> 1);
        float4 v = ((const float4*)x)[(size_t)token * 64 + lane];
        ushort4 o;
        o.x = f2bf(v.x); o.y = f2bf(v.y); o.z = f2bf(v.z); o.w = f2bf(v.w);
        ((ushort4*)xg)[(size_t)row * 64 + lane] = o;
    }
}

// ---------- grouped GEMM, 128x128 tile, 8 waves, BK=32, 3-buf counted-vmcnt ----------
// R10-verified config (82us/gemm2, occ 49%, conflicts 0). T4 counted vmcnt:
// 3 LDS buffers, prefetch 2 steps ahead, steady-state s_waitcnt vmcnt(2);
// vmcnt -> s_barrier -> issue stage(s+2) -> ds_read frags -> MFMA.
// LDS chunk-XOR swizzle (R8-verified conflicts=0). XCD remap pins experts to XCDs.
// mode 0: Hout = relu(acc+bias) bf16
// mode 1: outF[row][col] = acc + bias (plain fp32 store; combine applies weights)
template <int NCT>
__global__ __launch_bounds__(512, 4) void k_gemm(
    const unsigned short* __restrict__ A, const unsigned short* __restrict__ BT,
    const float* __restrict__ bias, const int* __restrict__ offs,
    const int* __restrict__ cnt, const int2* __restrict__ tab,
    const int* __restrict__ NT, int N, int K, int mode,
    unsigned short* __restrict__ Hout, float* __restrict__ outF,
    const int* __restrict__ rowTok, const float* __restrict__ rowW) {
    __shared__ __align__(16) unsigned short As[3][128 * 32];  // 3 x 8 KB
    __shared__ __align__(16) unsigned short Bs[3][128 * 32];  // 3 x 8 KB

    // flat = xcd + 8*(ct + NCT*qq) -> (ct, tIdx = 8*qq + xcd). Bijection for
    // gridDim.y = TABCAP = 520 = 65*8.
    unsigned flat = blockIdx.x + (unsigned)NCT * blockIdx.y;
    unsigned xcd = flat % 8u;
    unsigned q = flat / 8u;
    unsigned ct = q % (unsigned)NCT;
    unsigned tIdx = (q / (unsigned)NCT) * 8u + xcd;

    if (tIdx >= (unsigned)*NT || tIdx >= (unsigned)TABCAP) return;
    int2 ent = tab[tIdx];
    int e = ent.x, rt = ent.y;
    int cntE = cnt[e * CNT_STRIDE];
    int rowStart = offs[e] + rt * 128;
    int valid = cntE - rt * 128;
    if (valid > 128) valid = 128;

    int t = threadIdx.x;
    int lane = t & 63, wid = t >> 6;          // 8 waves
    int quad = lane >> 4, l15 = lane & 15;
    int waveM = wid >> 2, waveN = wid & 3;    // 2M x 4N: wave owns 64 rows x 32 cols

    const unsigned short* Ablk = A + (size_t)rowStart * K;
    const unsigned short* Bblk = BT + ((size_t)e * N + (size_t)ct * 128) * K;

    // staging: thread -> (row = t>>2 in 0..127, chunk = t&3); source chunk
    // swizzled skcs = skc ^ ((row>>1)&3). LDS linear [row][32] (G21): wave w
    // covers rows 16w..16w+15 -> base 512w elems, lane adds l*8.
    int srow = t >> 2, skc = t & 3;
    int skcs = skc ^ ((srow >> 1) & 3);
    int ar = min(srow, valid - 1);
    const unsigned short* ga = Ablk + (size_t)ar * K + skcs * 8;
    const unsigned short* gb = Bblk + (size_t)srow * K + skcs * 8;
    int la = wid * 512;

    auto stage = [&](int b, int kt) {
        gload_lds16(ga + kt, &As[b][la]);
        gload_lds16(gb + kt, &Bs[b][la]);
    };

    const f32x4 zero = {0.f, 0.f, 0.f, 0.f};
    f32x4 acc[4][2];
#pragma unroll
    for (int i = 0; i < 4; ++i)
#pragma unroll
        for (int j = 0; j < 2; ++j) acc[i][j] = zero;

    int xq = quad ^ ((l15 >> 1) & 3);   // swizzled read chunk
    int nst = K >> 5;                    // 8 or 16
    stage(0, 0);
    stage(1, 32);
    int bs = 0;
    for (int s = 0; s < nst; ++s) {
        if (s + 1 < nst) {
            asm volatile("s_waitcnt vmcnt(2)" ::: "memory");  // stage(s) done; stage(s+1) in flight
        } else {
            asm volatile("s_waitcnt vmcnt(0)" ::: "memory");  // last step: drain
        }
        __builtin_amdgcn_s_barrier();
        asm volatile("" ::: "memory");   // fence: no ds_read hoists above barrier
        if (s + 2 < nst) {
            int b2 = bs + 2; if (b2 >= 3) b2 -= 3;
            stage(b2, (s + 2) << 5);
        }
        const unsigned short* Ab = As[bs];
        const unsigned short* Bb = Bs[bs];
        bf16x8 af[4], bf[2];
#pragma unroll
        for (int i = 0; i < 4; ++i)
            af[i] = *(const bf16x8*)&Ab[(waveM * 64 + i * 16 + l15) * 32 + xq * 8];
#pragma unroll
        for (int j = 0; j < 2; ++j)
            bf[j] = *(const bf16x8*)&Bb[(waveN * 32 + j * 16 + l15) * 32 + xq * 8];
#pragma unroll
        for (int i = 0; i < 4; ++i)
#pragma unroll
            for (int j = 0; j < 2; ++j)
                acc[i][j] = __builtin_amdgcn_mfma_f32_16x16x32_bf16(af[i], bf[j], acc[i][j], 0, 0, 0);
        ++bs; if (bs == 3) bs = 0;
    }

    const float* be = bias + (size_t)e * N;
    if (mode == 0) {
#pragma unroll
        for (int i = 0; i < 4; ++i) {
#pragma unroll
            for (int r = 0; r < 4; ++r) {
                int rl = waveM * 64 + i * 16 + quad * 4 + r;
                if (rl < valid) {
                    size_t rowOff = (size_t)(rowStart + rl) * N;
#pragma unroll
                    for (int j = 0; j < 2; ++j) {
                        int col = (int)ct * 128 + waveN * 32 + j * 16 + l15;
                        float v = acc[i][j][r] + be[col];
                        Hout[rowOff + col] = f2bf(fmaxf(v, 0.f));
                    }
                }
            }
        }
    } else {
        // y[row][col] = acc + bias; weights applied in k_combine (same fp32
        // two-term sum as the old atomicAdd path -> bit-identical output)
#pragma unroll
        for (int i = 0; i < 4; ++i) {
#pragma unroll
            for (int r = 0; r < 4; ++r) {
                int rl = waveM * 64 + i * 16 + quad * 4 + r;
                if (rl < valid) {
                    float* yrow = outF + (size_t)(rowStart + rl) * N;
#pragma unroll
                    for (int j = 0; j < 2; ++j) {
                        int col = (int)ct * 128 + waveN * 32 + j * 16 + l15;
                        yrow[col] = acc[i][j][r] + be[col];
                    }
                }
            }
        }
    }
}

// ---------- combine: out[tok] = w0*y[row0] + w1*y[row1] ----------
__global__ __launch_bounds__(256) void k_combine(
    const float* __restrict__ y, const int2* __restrict__ tokRow,
    const float* __restrict__ rowW, float* __restrict__ out) {
    int gid = blockIdx.x * 256 + threadIdx.x;   // one float4 per thread
    int tok = gid >> 6;                          // 64 threads per token
    int cg = (gid & 63) << 2;
    int2 rr = tokRow[tok];
    float w0 = rowW[rr.x], w1 = rowW[rr.y];
    float4 a = *(const float4*)&y[(size_t)rr.x * DOUT + cg];
    float4 b = *(const float4*)&y[(size_t)rr.y * DOUT + cg];
    float4 o;
    o.x = w0 * a.x + w1 * b.x;
    o.y = w0 * a.y + w1 * b.y;
    o.z = w0 * a.z + w1 * b.z;
    o.w = w0 * a.w + w1 * b.w;
    *(float4*)&out[(size_t)tok * DOUT + cg] = o;
}

extern "C" void kernel_launch(void* const* d_in, const int* in_sizes, int n_in,
                              void* d_out, int out_size, void* d_ws, size_t ws_size,
                              hipStream_t stream) {
    const float* x   = (const float*)d_in[0];
    const float* gW1 = (const float*)d_in[1];
    const float* gb1 = (const float*)d_in[2];
    const float* gW2 = (const float*)d_in[3];
    const float* gb2 = (const float*)d_in[4];
    const float* We1 = (const float*)d_in[5];
    const float* be1 = (const float*)d_in[6];
    const float* We2 = (const float*)d_in[7];
    const float* be2 = (const float*)d_in[8];
    const float* We3 = (const float*)d_in[9];
    const float* be3 = (const float*)d_in[10];
    float* out = (float*)d_out;

    uint8_t* ws = (uint8_t*)d_ws;
    size_t off = 0;
    auto alloc = [&](size_t bytes) -> void* {
        void* p = ws + off;
        off += (bytes + 255) & ~(size_t)255;
        return p;
    };
    unsigned short* WT1 = (unsigned short*)alloc((size_t)E_ * HID * DIN * 2);   // [E][512][256]
    unsigned short* WT2 = (unsigned short*)alloc((size_t)E_ * HID * HID * 2);   // [E][512][512]
    unsigned short* WT3 = (unsigned short*)alloc((size_t)E_ * DOUT * HID * 2);  // [E][256][512]
    unsigned short* R1  = (unsigned short*)alloc((size_t)NROW * HID * 2);       // xg then h2
    unsigned short* h1  = (unsigned short*)alloc((size_t)NROW * HID * 2);       // h1 then y (fp32)
    float*  hG     = (float*)alloc((size_t)NTOK * GHID * 4);                    // gate hidden fp32
    int2*   tokE   = (int2*)alloc((size_t)NTOK * 8);
    float2* tokW   = (float2*)alloc((size_t)NTOK * 8);
    int*    rowTok = (int*)alloc((size_t)NROW * 4);
    float*  rowW   = (float*)alloc((size_t)NROW * 4);
    int2*   tokRow = (int2*)alloc((size_t)NTOK * 8);
    int*    cnt    = (int*)alloc(E_ * CNT_STRIDE * 4);
    int*    offs   = (int*)alloc(256);
    int*    fill   = (int*)alloc(256);
    int*    NT     = (int*)alloc(256);
    int2*   tab    = (int2*)alloc(TABCAP * 8);
    unsigned short* xg = R1;   // [NROW][256] bf16 (dead after gemm1)
    unsigned short* h2 = R1;   // [NROW][512] bf16 (written by gemm2)
    float* y = (float*)h1;     // [NROW][256] fp32 (h1 dead after gemm2)

    hipMemsetAsync(cnt, 0, E_ * CNT_STRIDE * 4, stream);

    k_transpose_bf16<<<dim3(DIN / 64, HID / 64, E_), 256, 0, stream>>>(We1, WT1, DIN, HID);
    k_transpose_bf16<<<dim3(HID / 64, HID / 64, E_), 256, 0, stream>>>(We2, WT2, HID, HID);
    k_transpose_bf16<<<dim3(HID / 64, DOUT / 64, E_), 256, 0, stream>>>(We3, WT3, HID, DOUT);

    k_gate1<<<NTOK / 128, 256, 0, stream>>>(x, gW1, gb1, hG);
    k_gate2<<<NTOK / 64, 256, 0, stream>>>(hG, gW2, gb2, tokE, tokW, cnt);
    k_route_setup<<<1, 64, 0, stream>>>(cnt, offs, fill, tab, NT, out);
    k_gather<<<NTOK / 256, 256, 0, stream>>>(x, tokE, tokW, offs, fill, rowTok, rowW,
                                             tokRow, xg);

    k_gemm<4><<<dim3(4, TABCAP), 512, 0, stream>>>(xg, WT1, be1, offs, cnt, tab, NT,
                                                   HID, DIN, 0, h1, nullptr, rowTok, rowW);
    k_gemm<4><<<dim3(4, TABCAP), 512, 0, stream>>>(h1, WT2, be2, offs, cnt, tab, NT,
                                                   HID, HID, 0, h2, nullptr, rowTok, rowW);
    k_gemm<2><<<dim3(2, TABCAP), 512, 0, stream>>>(h2, WT3, be3, offs, cnt, tab, NT,
                                                   DOUT, HID, 1, nullptr, y, rowTok, rowW);
    k_combine<<<NTOK * DOUT / 4 / 256, 256, 0, stream>>>(y, tokRow, rowW, out);
}

// Round 14
// 346.768 us; speedup vs baseline: 1.3695x; 1.0259x over previous
//
#include <hip/hip_runtime.h>
#include <stdint.h>

#define E_ 8
#define DIN 256
#define DOUT 256
#define HID 512
#define GHID 128
#define NTOK 32768
#define NROW (NTOK * 2)
#define TABCAP 520
#define CNT_STRIDE 32

typedef float f32x4 __attribute__((ext_vector_type(4)));
typedef short bf16x8 __attribute__((ext_vector_type(8)));

// fp32 -> bf16 round-to-nearest-even
__device__ __forceinline__ unsigned short f2bf(float f) {
    unsigned int u = __float_as_uint(f);
    u += 0x7FFFu + ((u >> 16) & 1u);
    return (unsigned short)(u >> 16);
}

// async global->LDS, 16B per lane; LDS base must be wave-uniform (HW adds lane*16)
__device__ __forceinline__ void gload_lds16(const void* g, void* l) {
    __builtin_amdgcn_global_load_lds(
        (const __attribute__((address_space(1))) unsigned int*)g,
        (__attribute__((address_space(3))) unsigned int*)l, 16, 0, 0);
}

// ---------- weight transpose + bf16 convert: W[e][K][N] -> WT[e][N][K] ----------
__global__ __launch_bounds__(256) void k_transpose_bf16(
    const float* __restrict__ src, unsigned short* __restrict__ dst, int K, int N) {
    __shared__ float tile[64][65];
    int e = blockIdx.z;
    int k0 = blockIdx.x * 64, n0 = blockIdx.y * 64;
    const float* s = src + (size_t)e * K * N;
    unsigned short* d = dst + (size_t)e * N * K;
    int col = threadIdx.x & 63, ri = threadIdx.x >> 6;
#pragma unroll
    for (int it = 0; it < 16; ++it) {
        int row = it * 4 + ri;
        tile[row][col] = s[(size_t)(k0 + row) * N + n0 + col];
    }
    __syncthreads();
#pragma unroll
    for (int it = 0; it < 16; ++it) {
        int nrow = it * 4 + ri;
        d[(size_t)(n0 + nrow) * K + k0 + col] = f2bf(tile[col][nrow]);
    }
}

// ---------- fused gate: h = relu(x@gW1+gb1) in regs -> LDS; logits/top2 in-block ----------
// Phase 1 = verified k_gate1 (128 tok x 128 hid, 8x8 acc/thread), epilogue writes
// the h tile to LDS instead of global (kills the 32MB hG round-trip + a launch).
// Phase 2 = verified k_gate2 logic at 2 lanes/token x 64 hid, shfl_xor(1) reduce.
__global__ __launch_bounds__(256) void k_gate(
    const float* __restrict__ x, const float* __restrict__ gW1,
    const float* __restrict__ gb1, const float* __restrict__ gW2,
    const float* __restrict__ gb2, int2* __restrict__ tokE,
    float2* __restrict__ tokW, int* __restrict__ cnt) {
    __shared__ float xT[32][132];   // [kk][tok]
    __shared__ float ws[32][132];   // [kk][hid]
    __shared__ float hs[128][132];  // h tile fp32 (67.6 KB)
    __shared__ float wg[GHID * E_]; // gW2 4 KB
    __shared__ int lcnt[E_];
    int t = threadIdx.x;
    int tokBase = blockIdx.x * 128;
    int tx = t & 15, ty = t >> 4;
    float acc[8][8];
#pragma unroll
    for (int i = 0; i < 8; ++i)
#pragma unroll
        for (int j = 0; j < 8; ++j) acc[i][j] = 0.f;

#pragma unroll
    for (int i = 0; i < 4; ++i) wg[i * 256 + t] = gW2[i * 256 + t];
    if (t < E_) lcnt[t] = 0;

    int stok = t >> 1;
    int skh = (t & 1) * 16;
    int wkk = t >> 3;
    int wh = (t & 7) * 16;

    for (int k0 = 0; k0 < DIN; k0 += 32) {
        const float* xr = x + (size_t)(tokBase + stok) * DIN + k0 + skh;
        float4 a0 = ((const float4*)xr)[0];
        float4 a1 = ((const float4*)xr)[1];
        float4 a2 = ((const float4*)xr)[2];
        float4 a3 = ((const float4*)xr)[3];
        xT[skh + 0][stok] = a0.x;  xT[skh + 1][stok] = a0.y;
        xT[skh + 2][stok] = a0.z;  xT[skh + 3][stok] = a0.w;
        xT[skh + 4][stok] = a1.x;  xT[skh + 5][stok] = a1.y;
        xT[skh + 6][stok] = a1.z;  xT[skh + 7][stok] = a1.w;
        xT[skh + 8][stok] = a2.x;  xT[skh + 9][stok] = a2.y;
        xT[skh + 10][stok] = a2.z; xT[skh + 11][stok] = a2.w;
        xT[skh + 12][stok] = a3.x; xT[skh + 13][stok] = a3.y;
        xT[skh + 14][stok] = a3.z; xT[skh + 15][stok] = a3.w;
        const float* wr = gW1 + (size_t)(k0 + wkk) * GHID + wh;
        *(float4*)&ws[wkk][wh + 0]  = ((const float4*)wr)[0];
        *(float4*)&ws[wkk][wh + 4]  = ((const float4*)wr)[1];
        *(float4*)&ws[wkk][wh + 8]  = ((const float4*)wr)[2];
        *(float4*)&ws[wkk][wh + 12] = ((const float4*)wr)[3];
        __syncthreads();
#pragma unroll 4
        for (int kk = 0; kk < 32; ++kk) {
            f32x4 wv0 = *(const f32x4*)&ws[kk][tx * 8];
            f32x4 wv1 = *(const f32x4*)&ws[kk][tx * 8 + 4];
            f32x4 xv0 = *(const f32x4*)&xT[kk][ty * 8];
            f32x4 xv1 = *(const f32x4*)&xT[kk][ty * 8 + 4];
            float xs[8] = {xv0.x, xv0.y, xv0.z, xv0.w, xv1.x, xv1.y, xv1.z, xv1.w};
            float wsv[8] = {wv0.x, wv0.y, wv0.z, wv0.w, wv1.x, wv1.y, wv1.z, wv1.w};
#pragma unroll
            for (int i = 0; i < 8; ++i)
#pragma unroll
                for (int j = 0; j < 8; ++j) acc[i][j] += xs[i] * wsv[j];
        }
        __syncthreads();
    }
    float4 b0 = *(const float4*)&gb1[tx * 8];
    float4 b1 = *(const float4*)&gb1[tx * 8 + 4];
#pragma unroll
    for (int i = 0; i < 8; ++i) {
        int trow = ty * 8 + i;
        float4 o0, o1;
        o0.x = fmaxf(acc[i][0] + b0.x, 0.f); o0.y = fmaxf(acc[i][1] + b0.y, 0.f);
        o0.z = fmaxf(acc[i][2] + b0.z, 0.f); o0.w = fmaxf(acc[i][3] + b0.w, 0.f);
        o1.x = fmaxf(acc[i][4] + b1.x, 0.f); o1.y = fmaxf(acc[i][5] + b1.y, 0.f);
        o1.z = fmaxf(acc[i][6] + b1.z, 0.f); o1.w = fmaxf(acc[i][7] + b1.w, 0.f);
        *(float4*)&hs[trow][tx * 8] = o0;
        *(float4*)&hs[trow][tx * 8 + 4] = o1;
    }
    __syncthreads();

    // phase 2: logits + top2. 2 lanes per token, 64 hid each.
    int tok = t >> 1, part = t & 1;
    float s[8];
#pragma unroll
    for (int e = 0; e < E_; ++e) s[e] = 0.f;
    const float* hr = &hs[tok][part * 64];
#pragma unroll 4
    for (int jq = 0; jq < 16; ++jq) {
        f32x4 hv = *(const f32x4*)&hr[jq * 4];
#pragma unroll
        for (int j = 0; j < 4; ++j) {
            float h = hv[j];
            int hidx = part * 64 + jq * 4 + j;
            f32x4 w0 = *(const f32x4*)&wg[hidx * 8];
            f32x4 w1 = *(const f32x4*)&wg[hidx * 8 + 4];
            s[0] += h * w0.x; s[1] += h * w0.y; s[2] += h * w0.z; s[3] += h * w0.w;
            s[4] += h * w1.x; s[5] += h * w1.y; s[6] += h * w1.z; s[7] += h * w1.w;
        }
    }
#pragma unroll
    for (int e = 0; e < E_; ++e) s[e] += __shfl_xor(s[e], 1);
    if (part == 0) {
        float l[8];
#pragma unroll
        for (int e = 0; e < E_; ++e) l[e] = s[e] + gb2[e];
        int i1 = 0; float b1v = l[0];
#pragma unroll
        for (int e = 1; e < E_; ++e) if (l[e] > b1v) { b1v = l[e]; i1 = e; }
        int i2 = -1; float b2v = -3.4e38f;
#pragma unroll
        for (int e = 0; e < E_; ++e) if (e != i1 && l[e] > b2v) { b2v = l[e]; i2 = e; }
        float mm = fmaxf(b1v, b2v);
        float p1 = expf(b1v - mm), p2 = expf(b2v - mm);
        float inv = 1.f / (p1 + p2);
        int gtok = tokBase + tok;
        tokE[gtok] = make_int2(i1, i2);
        tokW[gtok] = make_float2(p1 * inv, p2 * inv);
        atomicAdd(&lcnt[i1], 1);
        atomicAdd(&lcnt[i2], 1);
    }
    __syncthreads();
    if (t < E_) atomicAdd(&cnt[t * CNT_STRIDE], lcnt[t]);
}

// ---------- prefix offsets, tile work table, aux outputs (parallel fill) ----------
__global__ void k_route_setup(const int* __restrict__ cnt, int* __restrict__ offs,
                              int* __restrict__ fill, int2* __restrict__ tab,
                              int* __restrict__ NT, float* __restrict__ outTail) {
    int t = threadIdx.x;   // 64 threads
    int c[E_], nt[E_];
#pragma unroll
    for (int e = 0; e < E_; ++e) {
        c[e] = cnt[e * CNT_STRIDE];
        nt[e] = (c[e] + 127) >> 7;
    }
    if (t == 0) {
        int off = 0, ntp = 0;
        float bl = 0.f;
#pragma unroll
        for (int e = 0; e < E_; ++e) {
            offs[e] = off; off += c[e];
            fill[e] = 0;
            ntp += nt[e];
            float u = (float)c[e] / 32768.f;
            outTail[8388609 + e] = u;
            float dd = u - 0.125f;
            bl += dd * dd;
        }
        outTail[8388608] = bl * (0.01f / 8.f);
        *NT = ntp;
    }
    int maxnt = 0;
#pragma unroll
    for (int e = 0; e < E_; ++e) maxnt = max(maxnt, nt[e]);
    for (int k = t; k < maxnt; k += 64) {
        int p = 0;
#pragma unroll
        for (int e = 0; e < E_; ++e) p += min(nt[e], k);
#pragma unroll
        for (int e = 0; e < E_; ++e) {
            if (k < nt[e]) {
                tab[p] = make_int2(e, k);
                ++p;
            }
        }
    }
}

// ---------- gather: assign rows, record token/weight + tokRow, copy x to bf16 ----------
__global__ __launch_bounds__(256) void k_gather(
    const float* __restrict__ x, const int2* __restrict__ tokE,
    const float2* __restrict__ tokW, const int* __restrict__ offs,
    int* __restrict__ fill, int* __restrict__ rowTok, float* __restrict__ rowW,
    int2* __restrict__ tokRow, unsigned short* __restrict__ xg) {
    __shared__ int lc[E_], lbase[E_], lfill[E_];
    __shared__ int srow[512];
    int t = threadIdx.x;
    int tokBase = blockIdx.x * 256;
    if (t < E_) { lc[t] = 0; lfill[t] = 0; }
    __syncthreads();
    for (int s = t; s < 512; s += 256) {
        int token = tokBase + (s >> 1);
        int2 ee = tokE[token];
        int e = (s & 1) ? ee.y : ee.x;
        atomicAdd(&lc[e], 1);
    }
    __syncthreads();
    if (t < E_) lbase[t] = atomicAdd(&fill[t], lc[t]);
    __syncthreads();
    for (int s = t; s < 512; s += 256) {
        int token = tokBase + (s >> 1);
        int2 ee = tokE[token];
        float2 wv = tokW[token];
        int e; float w;
        if (s & 1) { e = ee.y; w = wv.y; } else { e = ee.x; w = wv.x; }
        int r = atomicAdd(&lfill[e], 1);
        int row = offs[e] + lbase[e] + r;
        srow[s] = row;
        rowTok[row] = token;
        rowW[row] = w;
        ((int*)&tokRow[token])[s & 1] = row;
    }
    __syncthreads();
    int wid = t >> 6, lane = t & 63;
    for (int s = wid; s < 512; s += 4) {
        int row = srow[s];
        int token = tokBase + (s >> 1);
        float4 v = ((const float4*)x)[(size_t)token * 64 + lane];
        ushort4 o;
        o.x = f2bf(v.x); o.y = f2bf(v.y); o.z = f2bf(v.z); o.w = f2bf(v.w);
        ((ushort4*)xg)[(size_t)row * 64 + lane] = o;
    }
}

// ---------- grouped GEMM, 128x128 tile, 8 waves, BK=32, 3-buf counted-vmcnt ----------
// R10/R13-verified config. T4 counted vmcnt: 3 LDS buffers, prefetch 2 ahead,
// steady-state s_waitcnt vmcnt(2) -> s_barrier -> stage(s+2) -> ds_read -> MFMA.
// LDS chunk-XOR swizzle (conflicts=0). XCD remap pins experts to XCDs.
// mode 0: Hout = relu(acc+bias) bf16
// mode 1: outF[row][col] = acc + bias (plain fp32 store; combine applies weights)
template <int NCT>
__global__ __launch_bounds__(512, 4) void k_gemm(
    const unsigned short* __restrict__ A, const unsigned short* __restrict__ BT,
    const float* __restrict__ bias, const int* __restrict__ offs,
    const int* __restrict__ cnt, const int2* __restrict__ tab,
    const int* __restrict__ NT, int N, int K, int mode,
    unsigned short* __restrict__ Hout, float* __restrict__ outF,
    const int* __restrict__ rowTok, const float* __restrict__ rowW) {
    __shared__ __align__(16) unsigned short As[3][128 * 32];  // 3 x 8 KB
    __shared__ __align__(16) unsigned short Bs[3][128 * 32];  // 3 x 8 KB

    unsigned flat = blockIdx.x + (unsigned)NCT * blockIdx.y;
    unsigned xcd = flat % 8u;
    unsigned q = flat / 8u;
    unsigned ct = q % (unsigned)NCT;
    unsigned tIdx = (q / (unsigned)NCT) * 8u + xcd;

    if (tIdx >= (unsigned)*NT || tIdx >= (unsigned)TABCAP) return;
    int2 ent = tab[tIdx];
    int e = ent.x, rt = ent.y;
    int cntE = cnt[e * CNT_STRIDE];
    int rowStart = offs[e] + rt * 128;
    int valid = cntE - rt * 128;
    if (valid > 128) valid = 128;

    int t = threadIdx.x;
    int lane = t & 63, wid = t >> 6;          // 8 waves
    int quad = lane >> 4, l15 = lane & 15;
    int waveM = wid >> 2, waveN = wid & 3;    // 2M x 4N: wave owns 64 rows x 32 cols

    const unsigned short* Ablk = A + (size_t)rowStart * K;
    const unsigned short* Bblk = BT + ((size_t)e * N + (size_t)ct * 128) * K;

    int srow = t >> 2, skc = t & 3;
    int skcs = skc ^ ((srow >> 1) & 3);
    int ar = min(srow, valid - 1);
    const unsigned short* ga = Ablk + (size_t)ar * K + skcs * 8;
    const unsigned short* gb = Bblk + (size_t)srow * K + skcs * 8;
    int la = wid * 512;

    auto stage = [&](int b, int kt) {
        gload_lds16(ga + kt, &As[b][la]);
        gload_lds16(gb + kt, &Bs[b][la]);
    };

    const f32x4 zero = {0.f, 0.f, 0.f, 0.f};
    f32x4 acc[4][2];
#pragma unroll
    for (int i = 0; i < 4; ++i)
#pragma unroll
        for (int j = 0; j < 2; ++j) acc[i][j] = zero;

    int xq = quad ^ ((l15 >> 1) & 3);   // swizzled read chunk
    int nst = K >> 5;                    // 8 or 16
    stage(0, 0);
    stage(1, 32);
    int bs = 0;
    for (int s = 0; s < nst; ++s) {
        if (s + 1 < nst) {
            asm volatile("s_waitcnt vmcnt(2)" ::: "memory");
        } else {
            asm volatile("s_waitcnt vmcnt(0)" ::: "memory");
        }
        __builtin_amdgcn_s_barrier();
        asm volatile("" ::: "memory");
        if (s + 2 < nst) {
            int b2 = bs + 2; if (b2 >= 3) b2 -= 3;
            stage(b2, (s + 2) << 5);
        }
        const unsigned short* Ab = As[bs];
        const unsigned short* Bb = Bs[bs];
        bf16x8 af[4], bf[2];
#pragma unroll
        for (int i = 0; i < 4; ++i)
            af[i] = *(const bf16x8*)&Ab[(waveM * 64 + i * 16 + l15) * 32 + xq * 8];
#pragma unroll
        for (int j = 0; j < 2; ++j)
            bf[j] = *(const bf16x8*)&Bb[(waveN * 32 + j * 16 + l15) * 32 + xq * 8];
#pragma unroll
        for (int i = 0; i < 4; ++i)
#pragma unroll
            for (int j = 0; j < 2; ++j)
                acc[i][j] = __builtin_amdgcn_mfma_f32_16x16x32_bf16(af[i], bf[j], acc[i][j], 0, 0, 0);
        ++bs; if (bs == 3) bs = 0;
    }

    const float* be = bias + (size_t)e * N;
    if (mode == 0) {
#pragma unroll
        for (int i = 0; i < 4; ++i) {
#pragma unroll
            for (int r = 0; r < 4; ++r) {
                int rl = waveM * 64 + i * 16 + quad * 4 + r;
                if (rl < valid) {
                    size_t rowOff = (size_t)(rowStart + rl) * N;
#pragma unroll
                    for (int j = 0; j < 2; ++j) {
                        int col = (int)ct * 128 + waveN * 32 + j * 16 + l15;
                        float v = acc[i][j][r] + be[col];
                        Hout[rowOff + col] = f2bf(fmaxf(v, 0.f));
                    }
                }
            }
        }
    } else {
#pragma unroll
        for (int i = 0; i < 4; ++i) {
#pragma unroll
            for (int r = 0; r < 4; ++r) {
                int rl = waveM * 64 + i * 16 + quad * 4 + r;
                if (rl < valid) {
                    float* yrow = outF + (size_t)(rowStart + rl) * N;
#pragma unroll
                    for (int j = 0; j < 2; ++j) {
                        int col = (int)ct * 128 + waveN * 32 + j * 16 + l15;
                        yrow[col] = acc[i][j][r] + be[col];
                    }
                }
            }
        }
    }
}

// ---------- combine: out[tok] = w0*y[row0] + w1*y[row1] ----------
__global__ __launch_bounds__(256) void k_combine(
    const float* __restrict__ y, const int2* __restrict__ tokRow,
    const float* __restrict__ rowW, float* __restrict__ out) {
    int gid = blockIdx.x * 256 + threadIdx.x;   // one float4 per thread
    int tok = gid >> 6;                          // 64 threads per token
    int cg = (gid & 63) << 2;
    int2 rr = tokRow[tok];
    float w0 = rowW[rr.x], w1 = rowW[rr.y];
    float4 a = *(const float4*)&y[(size_t)rr.x * DOUT + cg];
    float4 b = *(const float4*)&y[(size_t)rr.y * DOUT + cg];
    float4 o;
    o.x = w0 * a.x + w1 * b.x;
    o.y = w0 * a.y + w1 * b.y;
    o.z = w0 * a.z + w1 * b.z;
    o.w = w0 * a.w + w1 * b.w;
    *(float4*)&out[(size_t)tok * DOUT + cg] = o;
}

extern "C" void kernel_launch(void* const* d_in, const int* in_sizes, int n_in,
                              void* d_out, int out_size, void* d_ws, size_t ws_size,
                              hipStream_t stream) {
    const float* x   = (const float*)d_in[0];
    const float* gW1 = (const float*)d_in[1];
    const float* gb1 = (const float*)d_in[2];
    const float* gW2 = (const float*)d_in[3];
    const float* gb2 = (const float*)d_in[4];
    const float* We1 = (const float*)d_in[5];
    const float* be1 = (const float*)d_in[6];
    const float* We2 = (const float*)d_in[7];
    const float* be2 = (const float*)d_in[8];
    const float* We3 = (const float*)d_in[9];
    const float* be3 = (const float*)d_in[10];
    float* out = (float*)d_out;

    uint8_t* ws = (uint8_t*)d_ws;
    size_t off = 0;
    auto alloc = [&](size_t bytes) -> void* {
        void* p = ws + off;
        off += (bytes + 255) & ~(size_t)255;
        return p;
    };
    unsigned short* WT1 = (unsigned short*)alloc((size_t)E_ * HID * DIN * 2);   // [E][512][256]
    unsigned short* WT2 = (unsigned short*)alloc((size_t)E_ * HID * HID * 2);   // [E][512][512]
    unsigned short* WT3 = (unsigned short*)alloc((size_t)E_ * DOUT * HID * 2);  // [E][256][512]
    unsigned short* R1  = (unsigned short*)alloc((size_t)NROW * HID * 2);       // xg then h2
    unsigned short* h1  = (unsigned short*)alloc((size_t)NROW * HID * 2);       // h1 then y (fp32)
    int2*   tokE   = (int2*)alloc((size_t)NTOK * 8);
    float2* tokW   = (float2*)alloc((size_t)NTOK * 8);
    int*    rowTok = (int*)alloc((size_t)NROW * 4);
    float*  rowW   = (float*)alloc((size_t)NROW * 4);
    int2*   tokRow = (int2*)alloc((size_t)NTOK * 8);
    int*    cnt    = (int*)alloc(E_ * CNT_STRIDE * 4);
    int*    offs   = (int*)alloc(256);
    int*    fill   = (int*)alloc(256);
    int*    NT     = (int*)alloc(256);
    int2*   tab    = (int2*)alloc(TABCAP * 8);
    unsigned short* xg = R1;   // [NROW][256] bf16 (dead after gemm1)
    unsigned short* h2 = R1;   // [NROW][512] bf16 (written by gemm2)
    float* y = (float*)h1;     // [NROW][256] fp32 (h1 dead after gemm2)

    hipMemsetAsync(cnt, 0, E_ * CNT_STRIDE * 4, stream);

    k_transpose_bf16<<<dim3(DIN / 64, HID / 64, E_), 256, 0, stream>>>(We1, WT1, DIN, HID);
    k_transpose_bf16<<<dim3(HID / 64, HID / 64, E_), 256, 0, stream>>>(We2, WT2, HID, HID);
    k_transpose_bf16<<<dim3(HID / 64, DOUT / 64, E_), 256, 0, stream>>>(We3, WT3, HID, DOUT);

    k_gate<<<NTOK / 128, 256, 0, stream>>>(x, gW1, gb1, gW2, gb2, tokE, tokW, cnt);
    k_route_setup<<<1, 64, 0, stream>>>(cnt, offs, fill, tab, NT, out);
    k_gather<<<NTOK / 256, 256, 0, stream>>>(x, tokE, tokW, offs, fill, rowTok, rowW,
                                             tokRow, xg);

    k_gemm<4><<<dim3(4, TABCAP), 512, 0, stream>>>(xg, WT1, be1, offs, cnt, tab, NT,
                                                   HID, DIN, 0, h1, nullptr, rowTok, rowW);
    k_gemm<4><<<dim3(4, TABCAP), 512, 0, stream>>>(h1, WT2, be2, offs, cnt, tab, NT,
                                                   HID, HID, 0, h2, nullptr, rowTok, rowW);
    k_gemm<2><<<dim3(2, TABCAP), 512, 0, stream>>>(h2, WT3, be3, offs, cnt, tab, NT,
                                                   DOUT, HID, 1, nullptr, y, rowTok, rowW);
    k_combine<<<NTOK * DOUT / 4 / 256, 256, 0, stream>>>(y, tokRow, rowW, out);
}